// Round 5
// baseline (554.411 us; speedup 1.0000x reference)
//
#include <hip/hip_runtime.h>
#include <math.h>

// Problem constants
#define S_  1024
#define B_  8
#define D_  512
#define H_  8
#define HD_ 64
#define FF_ 2048
#define M_  8192   // S*B tokens; token r = s*B_ + b
#define DD_ (D_ * D_)

typedef __attribute__((ext_vector_type(8))) short short8;   // 8 x bf16
typedef __attribute__((ext_vector_type(4))) float f32x4;

static __device__ __forceinline__ unsigned short f2bf(float x) {
  union { float f; unsigned int u; } v; v.f = x;
  unsigned int r = v.u + 0x7fff + ((v.u >> 16) & 1);        // RNE
  return (unsigned short)(r >> 16);
}
static __device__ __forceinline__ float bf2f(unsigned short x) {
  union { unsigned int u; float f; } v; v.u = ((unsigned int)x) << 16;
  return v.f;
}
// pack two floats to 2 bf16 in one u32 (round-to-nearest-away)
static __device__ __forceinline__ unsigned int pack_bf2(float a, float b) {
  union { float f; unsigned int u; } x, y; x.f = a; y.f = b;
  return ((x.u + 0x8000u) >> 16) | ((y.u + 0x8000u) & 0xffff0000u);
}
// async global->LDS, 16B/lane; LDS dest = wave-uniform base + lane*16
static __device__ __forceinline__ void gl_lds16(const unsigned short* g, unsigned short* l) {
  __builtin_amdgcn_global_load_lds((__attribute__((address_space(1))) void*)(g),
                                   (__attribute__((address_space(3))) void*)(l), 16, 0, 0);
}

// ---------------------------------------------------------------------------
// merged conversions: blocks [0,6144): 6 weight jobs of 1,048,576 elems;
// blocks [6144,10240): single-pass activations (src,srcd,pos read once ->
// src16, srcd16, qkin16=bf16(src+pos))
// ---------------------------------------------------------------------------
struct CvtArgs {
  const float* win[6]; unsigned short* wout[6];
  const float* src; const float* srcd; const float* pos;
  unsigned short* src16; unsigned short* srcd16; unsigned short* qkin16;
};
__global__ __launch_bounds__(256) void cvt_kernel(CvtArgs a) {
  int bx = blockIdx.x;
  if (bx < 6144) {
    int job = bx >> 10;
    int i = ((bx & 1023) * 256 + threadIdx.x) * 4;
    float4 v = *(const float4*)(a.win[job] + i);
    unsigned short u[4] = {f2bf(v.x), f2bf(v.y), f2bf(v.z), f2bf(v.w)};
    *(uint2*)(a.wout[job] + i) = *(const uint2*)u;
  } else {
    int i = ((bx - 6144) * 256 + threadIdx.x) * 4;
    float4 s = *(const float4*)(a.src + i);
    float4 d = *(const float4*)(a.srcd + i);
    float4 p = *(const float4*)(a.pos + i);
    unsigned short us[4] = {f2bf(s.x), f2bf(s.y), f2bf(s.z), f2bf(s.w)};
    unsigned short ud[4] = {f2bf(d.x), f2bf(d.y), f2bf(d.z), f2bf(d.w)};
    unsigned short uq[4] = {f2bf(s.x + p.x), f2bf(s.y + p.y),
                            f2bf(s.z + p.z), f2bf(s.w + p.w)};
    *(uint2*)(a.src16 + i)  = *(const uint2*)us;
    *(uint2*)(a.srcd16 + i) = *(const uint2*)ud;
    *(uint2*)(a.qkin16 + i) = *(const uint2*)uq;
  }
}

// ---------------------------------------------------------------------------
// bf16 MFMA GEMM body (m97 structure): Y = X @ W^T + bias (+res) (+relu)
// 128x128 tile, BK=32, 256 thr = 4 waves (2x2 of 64x64), 16x16x32 MFMA.
// ---------------------------------------------------------------------------
static __device__ __forceinline__ void mgemm_body(
    const unsigned short* __restrict__ X, const unsigned short* __restrict__ W,
    const float* __restrict__ bias, const float* __restrict__ resf,
    const unsigned short* __restrict__ resb, unsigned short* __restrict__ Yb,
    float* __restrict__ Yf, int N, int K, int relu, int bx, int by,
    unsigned short* As, unsigned short* Bs)
{
  int tid = threadIdx.x;
  int lane = tid & 63, w = tid >> 6;
  int ml = lane & 15, g = lane >> 4;
  int wm = w >> 1, wn = w & 1;
  int m0 = by * 128, n0 = bx * 128;

  int lrow = w * 32 + (lane >> 2);
  int lcol = (lane & 3) * 8;
  const unsigned short* gA = X + (size_t)(m0 + lrow) * K + lcol;
  const unsigned short* gB = W + (size_t)(n0 + lrow) * K + lcol;
  unsigned short* lA = As + w * 1024;
  unsigned short* lB = Bs + w * 1024;

  f32x4 acc[4][4];
  #pragma unroll
  for (int i = 0; i < 4; i++)
    #pragma unroll
    for (int j = 0; j < 4; j++) acc[i][j] = (f32x4){0.f, 0.f, 0.f, 0.f};

  for (int k0 = 0; k0 < K; k0 += 32) {
    __syncthreads();
    gl_lds16(gA + k0, lA);
    gl_lds16(gA + k0 + (size_t)16 * K, lA + 512);
    gl_lds16(gB + k0, lB);
    gl_lds16(gB + k0 + (size_t)16 * K, lB + 512);
    __syncthreads();

    short8 af[4], bfr[4];
    #pragma unroll
    for (int i = 0; i < 4; i++)
      af[i] = *(const short8*)&As[(wm * 64 + i * 16 + ml) * 32 + g * 8];
    #pragma unroll
    for (int j = 0; j < 4; j++)
      bfr[j] = *(const short8*)&Bs[(wn * 64 + j * 16 + ml) * 32 + g * 8];
    #pragma unroll
    for (int i = 0; i < 4; i++)
      #pragma unroll
      for (int j = 0; j < 4; j++)
        acc[i][j] = __builtin_amdgcn_mfma_f32_16x16x32_bf16(af[i], bfr[j], acc[i][j], 0, 0, 0);
  }

  #pragma unroll
  for (int i = 0; i < 4; i++) {
    int grow = m0 + wm * 64 + i * 16 + g * 4;
    #pragma unroll
    for (int j = 0; j < 4; j++) {
      int gcol = n0 + wn * 64 + j * 16 + ml;
      float bv = bias[gcol];
      #pragma unroll
      for (int r = 0; r < 4; r++) {
        size_t idx = (size_t)(grow + r) * N + gcol;
        float v = acc[i][j][r] + bv;
        if (resf) v += resf[idx];
        if (resb) v += bf2f(resb[idx]);
        if (relu) v = fmaxf(v, 0.0f);
        if (Yb) Yb[idx] = f2bf(v);
        if (Yf) Yf[idx] = v;
      }
    }
  }
}

// QKV mega-launch: bx<8 img q,k (N=1024) | bx<12 img v (N=512) | else dpt qkv (N=1536)
__global__ __launch_bounds__(256) void qkv_kernel(
    const unsigned short* __restrict__ qkin, const unsigned short* __restrict__ src16,
    const unsigned short* __restrict__ srcd16,
    const unsigned short* __restrict__ w_i, const unsigned short* __restrict__ w_d,
    const float* __restrict__ bA_i, const float* __restrict__ bA_d,
    unsigned short* __restrict__ qkimg, unsigned short* __restrict__ vimg,
    unsigned short* __restrict__ dptqkv)
{
  __shared__ unsigned short As[128 * 32];
  __shared__ unsigned short Bs[128 * 32];
  int bx = blockIdx.x, by = blockIdx.y;
  if (bx < 8)
    mgemm_body(qkin, w_i, bA_i, nullptr, nullptr, qkimg, nullptr, 1024, 512, 0, bx, by, As, Bs);
  else if (bx < 12)
    mgemm_body(src16, w_i + 2 * DD_, bA_i + 1024, nullptr, nullptr, vimg, nullptr, 512, 512, 0, bx - 8, by, As, Bs);
  else
    mgemm_body(srcd16, w_d, bA_d, nullptr, nullptr, dptqkv, nullptr, 1536, 512, 0, bx - 12, by, As, Bs);
}

// img/dpt pair GEMM: blockIdx.z selects stream
__global__ __launch_bounds__(256) void pgemm_kernel(
    const unsigned short* __restrict__ X0, const unsigned short* __restrict__ X1,
    const unsigned short* __restrict__ W0, const unsigned short* __restrict__ W1,
    const float* __restrict__ b0, const float* __restrict__ b1,
    const float* __restrict__ rf0, const float* __restrict__ rf1,
    const unsigned short* __restrict__ rb0, const unsigned short* __restrict__ rb1,
    unsigned short* __restrict__ Y0, unsigned short* __restrict__ Y1,
    int N, int K, int relu)
{
  __shared__ unsigned short As[128 * 32];
  __shared__ unsigned short Bs[128 * 32];
  int z = blockIdx.z;
  mgemm_body(z ? X1 : X0, z ? W1 : W0, z ? b1 : b0, z ? rf1 : rf0,
             z ? rb1 : rb0, z ? Y1 : Y0, nullptr, N, K, relu,
             blockIdx.x, blockIdx.y, As, Bs);
}

// ---------------------------------------------------------------------------
// V transpose pair: v [M, ld] token-major head slice -> vt [B*H][64][1024]
// ---------------------------------------------------------------------------
__global__ __launch_bounds__(256) void vtrans_kernel(
    const unsigned short* __restrict__ v0, int ld0, unsigned short* __restrict__ vt0,
    const unsigned short* __restrict__ v1, int ld1, unsigned short* __restrict__ vt1)
{
  __shared__ unsigned short tile[64][72];
  const unsigned short* v = blockIdx.z ? v1 : v0;
  unsigned short* vt = blockIdx.z ? vt1 : vt0;
  int ld = blockIdx.z ? ld1 : ld0;
  int bh = blockIdx.y, b = bh >> 3, h = bh & 7;
  int s0 = blockIdx.x * 64;
  int tid = threadIdx.x;
  #pragma unroll
  for (int t = 0; t < 2; t++) {
    int idx = t * 256 + tid;
    int i = idx >> 3, c8 = (idx & 7) * 8;
    *(uint4*)&tile[i][c8] =
        *(const uint4*)(v + ((size_t)(s0 + i) * B_ + b) * ld + h * HD_ + c8);
  }
  __syncthreads();
  int hd = tid >> 2, j0 = (tid & 3) * 16;
  unsigned short tmp[16];
  #pragma unroll
  for (int j = 0; j < 16; j++) tmp[j] = tile[j0 + j][hd];
  unsigned short* dst = vt + ((size_t)bh * HD_ + hd) * S_ + s0 + j0;
  *(uint4*)(dst) = *(const uint4*)&tmp[0];
  *(uint4*)(dst + 8) = *(const uint4*)&tmp[8];
}

// ---------------------------------------------------------------------------
// LayerNorm pair, bf16 in: rows 0..8191 stream0, 8192..16383 stream1
// ---------------------------------------------------------------------------
__global__ __launch_bounds__(256) void ln16_kernel(
    const unsigned short* __restrict__ X0, const unsigned short* __restrict__ X1,
    unsigned short* __restrict__ Yb0, unsigned short* __restrict__ Yb1,
    float* __restrict__ Yf0, float* __restrict__ Yf1,
    const float* __restrict__ gb0, const float* __restrict__ gb1)
{
  int row = blockIdx.x, tid = threadIdx.x;
  int strm = row >> 13, r = row & 8191;
  const unsigned short* X = strm ? X1 : X0;
  unsigned short* Yb = strm ? Yb1 : Yb0;
  float* Yf = strm ? Yf1 : Yf0;
  const float* gb = strm ? gb1 : gb0;       // gamma at [0,512), beta at [512,1024)

  ushort2 xv = *(const ushort2*)(X + (size_t)r * D_ + 2 * tid);
  float v0 = bf2f(xv.x), v1 = bf2f(xv.y);
  float s = v0 + v1, q = v0 * v0 + v1 * v1;
  #pragma unroll
  for (int msk = 1; msk < 64; msk <<= 1) {
    s += __shfl_xor(s, msk);
    q += __shfl_xor(q, msk);
  }
  __shared__ float ss[4], qs[4];
  int wid = tid >> 6;
  if ((tid & 63) == 0) { ss[wid] = s; qs[wid] = q; }
  __syncthreads();
  s = ss[0] + ss[1] + ss[2] + ss[3];
  q = qs[0] + qs[1] + qs[2] + qs[3];
  float mean = s * (1.0f / D_);
  float var  = q * (1.0f / D_) - mean * mean;
  float inv  = rsqrtf(var + 1e-5f);
  float2 gg = *(const float2*)(gb + 2 * tid);
  float2 bb = *(const float2*)(gb + 512 + 2 * tid);
  float o0 = (v0 - mean) * inv * gg.x + bb.x;
  float o1 = (v1 - mean) * inv * gg.y + bb.y;
  if (Yb) {
    unsigned short u[2] = {f2bf(o0), f2bf(o1)};
    *(unsigned int*)(Yb + (size_t)r * D_ + 2 * tid) = *(const unsigned int*)u;
  }
  if (Yf) {
    float2 o; o.x = o0; o.y = o1;
    *(float2*)(Yf + (size_t)r * D_ + 2 * tid) = o;
  }
}

// ---------------------------------------------------------------------------
// MFMA dual-stream cross-blended flash attention v3.
// 512 threads = 8 waves, each owning 16 q-rows (Q-tile 128). K-tiles of 64.
// 16 waves/CU resident (LDS 68KB -> 2 blocks/CU) for latency hiding.
// QK computed transposed (A=K, B=Q -> C[key][q]); P packs along regs -> b64
// LDS writes (stride 72: conflict-free-ish). K/V staged via global_load_lds
// into unpadded [64][64] tiles, XOR-chunk swizzle. Plain exp2 (logits tiny)
// == exact softmax. 4 accumulators, blend 0.5/0.5 at end.
// XCD swizzle: the 8 q-blocks of one (b,h) land on one XCD for K/V L2 reuse.
// ---------------------------------------------------------------------------
__global__ __launch_bounds__(512, 4) void attn_kernel(
    const unsigned short* __restrict__ Qi, const unsigned short* __restrict__ Ki, int ldi,
    const unsigned short* __restrict__ Vti,
    const unsigned short* __restrict__ Qd, const unsigned short* __restrict__ Kd, int ldd,
    const unsigned short* __restrict__ Vtd,
    unsigned short* __restrict__ oi, unsigned short* __restrict__ od)
{
  __shared__ __align__(16) unsigned short Kls[2][64 * 64];   // [stream][key][dim] swizzled
  __shared__ __align__(16) unsigned short Vls[2][64 * 64];   // [stream][dim][key] swizzled
  __shared__ __align__(16) unsigned short Pl[8][2][16 * 72]; // [wave][stream][q][key] stride 72

  int tid = threadIdx.x;
  // XCD-aware swizzle: id bits (hi:3)(qb:3)(lo:3); bh = lo + hi*8, qb = mid
  int id = blockIdx.y * 8 + blockIdx.x;      // 0..511
  int bh = (id & 7) | ((id >> 6) << 3);
  int qb = (id >> 3) & 7;
  int b = bh >> 3, h = bh & 7;
  int q0 = qb * 128;

  int lane = tid & 63, w = tid >> 6;         // w = 0..7
  int ml = lane & 15, g = lane >> 4;
  int mx = ml & 7;                           // XOR swizzle term

  // Q fragments (B-operand): lane holds Q[q=q0+w*16+ml][dims g*8(+32)]
  short8 qf[2][2];                           // [stream][k-half]
  {
    size_t tok = (size_t)(q0 + w * 16 + ml) * B_ + b;
    const unsigned short* qa_i = Qi + tok * ldi + h * HD_ + g * 8;
    const unsigned short* qa_d = Qd + tok * ldd + h * HD_ + g * 8;
    qf[0][0] = *(const short8*)(qa_i);  qf[0][1] = *(const short8*)(qa_i + 32);
    qf[1][0] = *(const short8*)(qa_d);  qf[1][1] = *(const short8*)(qa_d + 32);
  }

  // staging: role = w&3 (K img, K dpt, V img, V dpt); half = w>>2 (rows 0-31/32-63)
  int role = w & 3, half4 = (w >> 2) * 4;
  int srow = lane >> 3;                      // 0..7
  int chg = (lane & 7) ^ srow;               // XOR-swizzled chunk slot
  const unsigned short* gbase; size_t s1, s2; unsigned short* lbase;
  if (role == 0)      { gbase = Ki  + ((size_t)srow * B_ + b) * ldi + h * HD_ + chg * 8; s1 = (size_t)B_ * ldi; s2 = s1; lbase = &Kls[0][0]; }
  else if (role == 1) { gbase = Kd  + ((size_t)srow * B_ + b) * ldd + h * HD_ + chg * 8; s1 = (size_t)B_ * ldd; s2 = s1; lbase = &Kls[1][0]; }
  else if (role == 2) { gbase = Vti + (size_t)bh * HD_ * S_ + (size_t)srow * S_ + chg * 8; s1 = S_; s2 = 1; lbase = &Vls[0][0]; }
  else                { gbase = Vtd + (size_t)bh * HD_ * S_ + (size_t)srow * S_ + chg * 8; s1 = S_; s2 = 1; lbase = &Vls[1][0]; }

  f32x4 acc4[4][4];                          // [combo: ii,di,id,dd][hd-tile]
  #pragma unroll
  for (int cb = 0; cb < 4; cb++)
    #pragma unroll
    for (int n = 0; n < 4; n++) acc4[cb][n] = (f32x4){0.f, 0.f, 0.f, 0.f};
  float lI = 0.f, lD = 0.f;
  const float SC = 0.18033688011112042f;     // 0.125 * log2(e)

  for (int kt = 0; kt < S_ / 64; kt++) {
    int k0 = kt * 64;
    __syncthreads();
    {
      const unsigned short* gp = gbase + (size_t)k0 * s2;
      #pragma unroll
      for (int rr2 = 0; rr2 < 4; rr2++) {
        int rr = half4 + rr2;
        gl_lds16(gp + (size_t)rr * 8 * s1, lbase + rr * 512);
      }
    }
    __syncthreads();

    // ---- K^T Q: C[key][q=ml], key tiles n of 16 ----
    #pragma unroll
    for (int st = 0; st < 2; st++) {
      float* ls = st ? &lD : &lI;
      const unsigned short* Kt = &Kls[st][0];
      #pragma unroll
      for (int n = 0; n < 4; n++) {
        int rbase = (n * 16 + ml) * 64;
        short8 kf0 = *(const short8*)&Kt[rbase + ((g ^ mx) * 8)];
        short8 kf1 = *(const short8*)&Kt[rbase + (((g + 4) ^ mx) * 8)];
        f32x4 a = (f32x4){0.f, 0.f, 0.f, 0.f};
        a = __builtin_amdgcn_mfma_f32_16x16x32_bf16(kf0, qf[st][0], a, 0, 0, 0);
        a = __builtin_amdgcn_mfma_f32_16x16x32_bf16(kf1, qf[st][1], a, 0, 0, 0);
        float p0 = exp2f(a[0] * SC), p1 = exp2f(a[1] * SC);
        float p2 = exp2f(a[2] * SC), p3 = exp2f(a[3] * SC);
        *ls += (p0 + p1) + (p2 + p3);
        uint2 pk; pk.x = pack_bf2(p0, p1); pk.y = pack_bf2(p2, p3);
        *(uint2*)&Pl[w][st][ml * 72 + n * 16 + g * 4] = pk;  // P[q=ml][keys n*16+g*4..+3]
      }
    }
    // ---- PV: 4 combos, key-dim 64 in 2 chunks of 32 ----
    #pragma unroll
    for (int c = 0; c < 2; c++) {
      short8 pI = *(const short8*)&Pl[w][0][ml * 72 + g * 8 + c * 32];
      short8 pD = *(const short8*)&Pl[w][1][ml * 72 + g * 8 + c * 32];
      #pragma unroll
      for (int n = 0; n < 4; n++) {
        int rbase = (n * 16 + ml) * 64;
        int sc = ((g + 4 * c) ^ mx) * 8;
        short8 vI = *(const short8*)&Vls[0][rbase + sc];
        short8 vD = *(const short8*)&Vls[1][rbase + sc];
        acc4[0][n] = __builtin_amdgcn_mfma_f32_16x16x32_bf16(pI, vI, acc4[0][n], 0, 0, 0);
        acc4[1][n] = __builtin_amdgcn_mfma_f32_16x16x32_bf16(pD, vI, acc4[1][n], 0, 0, 0);
        acc4[2][n] = __builtin_amdgcn_mfma_f32_16x16x32_bf16(pI, vD, acc4[2][n], 0, 0, 0);
        acc4[3][n] = __builtin_amdgcn_mfma_f32_16x16x32_bf16(pD, vD, acc4[3][n], 0, 0, 0);
      }
    }
  }

  // denominators: lane holds partial (16 keys/ktile) for q=ml; reduce over g
  lI += __shfl_xor(lI, 16);  lI += __shfl_xor(lI, 32);
  lD += __shfl_xor(lD, 16);  lD += __shfl_xor(lD, 32);
  float invI = 1.0f / lI, invD = 1.0f / lD;

  #pragma unroll
  for (int r = 0; r < 4; r++) {
    float iI = __shfl(invI, g * 4 + r, 16);  // denom for q-row g*4+r lives at lane ml=q
    float iD = __shfl(invD, g * 4 + r, 16);
    int qrow = q0 + w * 16 + g * 4 + r;
    size_t ob = ((size_t)qrow * B_ + b) * D_ + h * HD_;
    #pragma unroll
    for (int n = 0; n < 4; n++) {
      oi[ob + n * 16 + ml] = f2bf(0.5f * (acc4[0][n][r] * iI + acc4[1][n][r] * iD));
      od[ob + n * 16 + ml] = f2bf(0.5f * (acc4[3][n][r] * iD + acc4[2][n][r] * iI));
    }
  }
}

// ---------------------------------------------------------------------------
extern "C" void kernel_launch(void* const* d_in, const int* in_sizes, int n_in,
                              void* d_out, int out_size, void* d_ws, size_t ws_size,
                              hipStream_t stream) {
  const float* src  = (const float*)d_in[0];
  const float* srcd = (const float*)d_in[1];
  const float* pos  = (const float*)d_in[2];
  const float* wA_i = (const float*)d_in[3];
  const float* bA_i = (const float*)d_in[4];
  const float* wA_d = (const float*)d_in[5];
  const float* bA_d = (const float*)d_in[6];
  const float* w1_i = (const float*)d_in[7];
  const float* b1_i = (const float*)d_in[8];
  const float* w2_i = (const float*)d_in[9];
  const float* b2_i = (const float*)d_in[10];
  const float* w1_d = (const float*)d_in[11];
  const float* b1_d = (const float*)d_in[12];
  const float* w2_d = (const float*)d_in[13];
  const float* b2_d = (const float*)d_in[14];
  const float* ln_i = (const float*)d_in[15];
  const float* ln_d = (const float*)d_in[16];

  float* out = (float*)d_out;
  unsigned short* u = (unsigned short*)d_ws;
  const size_t T4 = (size_t)M_ * D_;          // 4,194,304
  const size_t WSZ = (size_t)FF_ * D_;        // 1,048,576 (== 4*DD_)

  // ---- workspace layout (units of T4 ushorts = 8.39 MB; total ~113 MB) ----
  unsigned short* src16  = u;                 // [0,1) -> vt_i after QKV
  unsigned short* srcd16 = u + T4;            // [1,2) -> vt_d after QKV
  unsigned short* qkimg  = u + 2 * T4;        // [2,4)  [M,1024]
  unsigned short* vimg   = u + 4 * T4;        // [4,5)  [M,512]
  unsigned short* dptqkv = u + 5 * T4;        // [5,8)  [M,1536]
  unsigned short* w_i16  = u + 8 * T4;        // weights: 6 x 1,048,576
  unsigned short* w_d16  = w_i16 + WSZ;
  unsigned short* w1i16  = w_d16 + WSZ;
  unsigned short* w2i16  = w1i16 + WSZ;
  unsigned short* w1d16  = w2i16 + WSZ;
  unsigned short* w2d16  = w1d16 + WSZ;
  unsigned short* t16_i  = w2d16 + WSZ;       // pre-LN bf16
  unsigned short* t16_d  = t16_i + T4;
  unsigned short* x16_i  = t16_d + T4;        // post-LN1
  unsigned short* x16_d  = x16_i + T4;
  unsigned short* vt_i   = src16;             // reuse after QKV
  unsigned short* vt_d   = srcd16;
  unsigned short* h16_i  = u;                 // [0,4) FFN hidden (post-attn reuse)
  unsigned short* h16_d  = u + 4 * T4;        // [4,8)
  // d_out overlays (consumed before final LN writes)
  unsigned short* qkin16 = (unsigned short*)out;          // bytes [0, 2T4)
  unsigned short* oi16   = (unsigned short*)out;          // bytes [0, 2T4)
  unsigned short* od16   = (unsigned short*)out + T4;     // bytes [2T4, 4T4)

  dim3 blk(256);

  CvtArgs ca;
  ca.win[0] = wA_i; ca.wout[0] = w_i16;
  ca.win[1] = wA_d; ca.wout[1] = w_d16;
  ca.win[2] = w1_i; ca.wout[2] = w1i16;
  ca.win[3] = w2_i; ca.wout[3] = w2i16;
  ca.win[4] = w1_d; ca.wout[4] = w1d16;
  ca.win[5] = w2_d; ca.wout[5] = w2d16;
  ca.src = src; ca.srcd = srcd; ca.pos = pos;
  ca.src16 = src16; ca.srcd16 = srcd16; ca.qkin16 = qkin16;
  cvt_kernel<<<10240, blk, 0, stream>>>(ca);

  qkv_kernel<<<dim3(24, 64), blk, 0, stream>>>(qkin16, src16, srcd16, w_i16, w_d16,
                                               bA_i, bA_d, qkimg, vimg, dptqkv);
  vtrans_kernel<<<dim3(16, 64, 2), blk, 0, stream>>>(vimg, 512, vt_i, dptqkv + 1024, 1536, vt_d);

  attn_kernel<<<dim3(8, 64), dim3(512), 0, stream>>>(
      qkimg, qkimg + 512, 1024, vt_i, dptqkv, dptqkv + 512, 1536, vt_d, oi16, od16);

  // out-proj + residual(src fp32) -> pre-LN bf16
  pgemm_kernel<<<dim3(4, 64, 2), blk, 0, stream>>>(
      oi16, od16, w_i16 + 3 * DD_, w_d16 + 3 * DD_, bA_i + 1536, bA_d + 1536,
      src, srcd, nullptr, nullptr, t16_i, t16_d, 512, 512, 0);
  ln16_kernel<<<2 * M_, blk, 0, stream>>>(t16_i, t16_d, x16_i, x16_d,
                                          nullptr, nullptr, ln_i, ln_d);
  pgemm_kernel<<<dim3(16, 64, 2), blk, 0, stream>>>(
      x16_i, x16_d, w1i16, w1d16, b1_i, b1_d,
      nullptr, nullptr, nullptr, nullptr, h16_i, h16_d, 2048, 512, 1);
  pgemm_kernel<<<dim3(4, 64, 2), blk, 0, stream>>>(
      h16_i, h16_d, w2i16, w2d16, b2_i, b2_d,
      nullptr, nullptr, x16_i, x16_d, t16_i, t16_d, 512, 2048, 0);
  ln16_kernel<<<2 * M_, blk, 0, stream>>>(t16_i, t16_d, nullptr, nullptr,
                                          out, out + T4, ln_i + 2 * D_, ln_d + 2 * D_);
}

// Round 6
// 477.185 us; speedup vs baseline: 1.1618x; 1.1618x over previous
//
#include <hip/hip_runtime.h>
#include <math.h>

// Problem constants
#define S_  1024
#define B_  8
#define D_  512
#define H_  8
#define HD_ 64
#define FF_ 2048
#define M_  8192   // S*B tokens; token r = s*B_ + b
#define DD_ (D_ * D_)

typedef __attribute__((ext_vector_type(8))) short short8;   // 8 x bf16
typedef __attribute__((ext_vector_type(4))) float f32x4;

static __device__ __forceinline__ unsigned short f2bf(float x) {
  union { float f; unsigned int u; } v; v.f = x;
  unsigned int r = v.u + 0x7fff + ((v.u >> 16) & 1);        // RNE
  return (unsigned short)(r >> 16);
}
static __device__ __forceinline__ float bf2f(unsigned short x) {
  union { unsigned int u; float f; } v; v.u = ((unsigned int)x) << 16;
  return v.f;
}
// pack two floats to 2 bf16 in one u32 (round-to-nearest-away)
static __device__ __forceinline__ unsigned int pack_bf2(float a, float b) {
  union { float f; unsigned int u; } x, y; x.f = a; y.f = b;
  return ((x.u + 0x8000u) >> 16) | ((y.u + 0x8000u) & 0xffff0000u);
}
// async global->LDS, 16B/lane; LDS dest = wave-uniform base + lane*16
static __device__ __forceinline__ void gl_lds16(const unsigned short* g, unsigned short* l) {
  __builtin_amdgcn_global_load_lds((__attribute__((address_space(1))) void*)(g),
                                   (__attribute__((address_space(3))) void*)(l), 16, 0, 0);
}

// ---------------------------------------------------------------------------
// merged conversions: blocks [0,6144): 6 weight jobs of 1,048,576 elems;
// blocks [6144,10240): single-pass activations (src,srcd,pos read once ->
// src16, srcd16, qkin16=bf16(src+pos))
// ---------------------------------------------------------------------------
struct CvtArgs {
  const float* win[6]; unsigned short* wout[6];
  const float* src; const float* srcd; const float* pos;
  unsigned short* src16; unsigned short* srcd16; unsigned short* qkin16;
};
__global__ __launch_bounds__(256) void cvt_kernel(CvtArgs a) {
  int bx = blockIdx.x;
  if (bx < 6144) {
    int job = bx >> 10;
    int i = ((bx & 1023) * 256 + threadIdx.x) * 4;
    float4 v = *(const float4*)(a.win[job] + i);
    unsigned short u[4] = {f2bf(v.x), f2bf(v.y), f2bf(v.z), f2bf(v.w)};
    *(uint2*)(a.wout[job] + i) = *(const uint2*)u;
  } else {
    int i = ((bx - 6144) * 256 + threadIdx.x) * 4;
    float4 s = *(const float4*)(a.src + i);
    float4 d = *(const float4*)(a.srcd + i);
    float4 p = *(const float4*)(a.pos + i);
    unsigned short us[4] = {f2bf(s.x), f2bf(s.y), f2bf(s.z), f2bf(s.w)};
    unsigned short ud[4] = {f2bf(d.x), f2bf(d.y), f2bf(d.z), f2bf(d.w)};
    unsigned short uq[4] = {f2bf(s.x + p.x), f2bf(s.y + p.y),
                            f2bf(s.z + p.z), f2bf(s.w + p.w)};
    *(uint2*)(a.src16 + i)  = *(const uint2*)us;
    *(uint2*)(a.srcd16 + i) = *(const uint2*)ud;
    *(uint2*)(a.qkin16 + i) = *(const uint2*)uq;
  }
}

// ---------------------------------------------------------------------------
// bf16 MFMA GEMM body (m97 structure): Y = X @ W^T + bias (+res) (+relu)
// 128x128 tile, BK=32, 256 thr = 4 waves (2x2 of 64x64), 16x16x32 MFMA.
// ---------------------------------------------------------------------------
static __device__ __forceinline__ void mgemm_body(
    const unsigned short* __restrict__ X, const unsigned short* __restrict__ W,
    const float* __restrict__ bias, const float* __restrict__ resf,
    const unsigned short* __restrict__ resb, unsigned short* __restrict__ Yb,
    float* __restrict__ Yf, int N, int K, int relu, int bx, int by,
    unsigned short* As, unsigned short* Bs)
{
  int tid = threadIdx.x;
  int lane = tid & 63, w = tid >> 6;
  int ml = lane & 15, g = lane >> 4;
  int wm = w >> 1, wn = w & 1;
  int m0 = by * 128, n0 = bx * 128;

  int lrow = w * 32 + (lane >> 2);
  int lcol = (lane & 3) * 8;
  const unsigned short* gA = X + (size_t)(m0 + lrow) * K + lcol;
  const unsigned short* gB = W + (size_t)(n0 + lrow) * K + lcol;
  unsigned short* lA = As + w * 1024;
  unsigned short* lB = Bs + w * 1024;

  f32x4 acc[4][4];
  #pragma unroll
  for (int i = 0; i < 4; i++)
    #pragma unroll
    for (int j = 0; j < 4; j++) acc[i][j] = (f32x4){0.f, 0.f, 0.f, 0.f};

  for (int k0 = 0; k0 < K; k0 += 32) {
    __syncthreads();
    gl_lds16(gA + k0, lA);
    gl_lds16(gA + k0 + (size_t)16 * K, lA + 512);
    gl_lds16(gB + k0, lB);
    gl_lds16(gB + k0 + (size_t)16 * K, lB + 512);
    __syncthreads();

    short8 af[4], bfr[4];
    #pragma unroll
    for (int i = 0; i < 4; i++)
      af[i] = *(const short8*)&As[(wm * 64 + i * 16 + ml) * 32 + g * 8];
    #pragma unroll
    for (int j = 0; j < 4; j++)
      bfr[j] = *(const short8*)&Bs[(wn * 64 + j * 16 + ml) * 32 + g * 8];
    #pragma unroll
    for (int i = 0; i < 4; i++)
      #pragma unroll
      for (int j = 0; j < 4; j++)
        acc[i][j] = __builtin_amdgcn_mfma_f32_16x16x32_bf16(af[i], bfr[j], acc[i][j], 0, 0, 0);
  }

  #pragma unroll
  for (int i = 0; i < 4; i++) {
    int grow = m0 + wm * 64 + i * 16 + g * 4;
    #pragma unroll
    for (int j = 0; j < 4; j++) {
      int gcol = n0 + wn * 64 + j * 16 + ml;
      float bv = bias[gcol];
      #pragma unroll
      for (int r = 0; r < 4; r++) {
        size_t idx = (size_t)(grow + r) * N + gcol;
        float v = acc[i][j][r] + bv;
        if (resf) v += resf[idx];
        if (resb) v += bf2f(resb[idx]);
        if (relu) v = fmaxf(v, 0.0f);
        if (Yb) Yb[idx] = f2bf(v);
        if (Yf) Yf[idx] = v;
      }
    }
  }
}

// QKV mega-launch: bx<8 img q,k (N=1024) | bx<12 img v (N=512) | else dpt qkv (N=1536)
__global__ __launch_bounds__(256) void qkv_kernel(
    const unsigned short* __restrict__ qkin, const unsigned short* __restrict__ src16,
    const unsigned short* __restrict__ srcd16,
    const unsigned short* __restrict__ w_i, const unsigned short* __restrict__ w_d,
    const float* __restrict__ bA_i, const float* __restrict__ bA_d,
    unsigned short* __restrict__ qkimg, unsigned short* __restrict__ vimg,
    unsigned short* __restrict__ dptqkv)
{
  __shared__ unsigned short As[128 * 32];
  __shared__ unsigned short Bs[128 * 32];
  int bx = blockIdx.x, by = blockIdx.y;
  if (bx < 8)
    mgemm_body(qkin, w_i, bA_i, nullptr, nullptr, qkimg, nullptr, 1024, 512, 0, bx, by, As, Bs);
  else if (bx < 12)
    mgemm_body(src16, w_i + 2 * DD_, bA_i + 1024, nullptr, nullptr, vimg, nullptr, 512, 512, 0, bx - 8, by, As, Bs);
  else
    mgemm_body(srcd16, w_d, bA_d, nullptr, nullptr, dptqkv, nullptr, 1536, 512, 0, bx - 12, by, As, Bs);
}

// img/dpt pair GEMM: blockIdx.z selects stream
__global__ __launch_bounds__(256) void pgemm_kernel(
    const unsigned short* __restrict__ X0, const unsigned short* __restrict__ X1,
    const unsigned short* __restrict__ W0, const unsigned short* __restrict__ W1,
    const float* __restrict__ b0, const float* __restrict__ b1,
    const float* __restrict__ rf0, const float* __restrict__ rf1,
    const unsigned short* __restrict__ rb0, const unsigned short* __restrict__ rb1,
    unsigned short* __restrict__ Y0, unsigned short* __restrict__ Y1,
    int N, int K, int relu)
{
  __shared__ unsigned short As[128 * 32];
  __shared__ unsigned short Bs[128 * 32];
  int z = blockIdx.z;
  mgemm_body(z ? X1 : X0, z ? W1 : W0, z ? b1 : b0, z ? rf1 : rf0,
             z ? rb1 : rb0, z ? Y1 : Y0, nullptr, N, K, relu,
             blockIdx.x, blockIdx.y, As, Bs);
}

// ---------------------------------------------------------------------------
// V transpose pair: v [M, ld] token-major head slice -> vt [B*H][64][1024]
// ---------------------------------------------------------------------------
__global__ __launch_bounds__(256) void vtrans_kernel(
    const unsigned short* __restrict__ v0, int ld0, unsigned short* __restrict__ vt0,
    const unsigned short* __restrict__ v1, int ld1, unsigned short* __restrict__ vt1)
{
  __shared__ unsigned short tile[64][72];
  const unsigned short* v = blockIdx.z ? v1 : v0;
  unsigned short* vt = blockIdx.z ? vt1 : vt0;
  int ld = blockIdx.z ? ld1 : ld0;
  int bh = blockIdx.y, b = bh >> 3, h = bh & 7;
  int s0 = blockIdx.x * 64;
  int tid = threadIdx.x;
  #pragma unroll
  for (int t = 0; t < 2; t++) {
    int idx = t * 256 + tid;
    int i = idx >> 3, c8 = (idx & 7) * 8;
    *(uint4*)&tile[i][c8] =
        *(const uint4*)(v + ((size_t)(s0 + i) * B_ + b) * ld + h * HD_ + c8);
  }
  __syncthreads();
  int hd = tid >> 2, j0 = (tid & 3) * 16;
  unsigned short tmp[16];
  #pragma unroll
  for (int j = 0; j < 16; j++) tmp[j] = tile[j0 + j][hd];
  unsigned short* dst = vt + ((size_t)bh * HD_ + hd) * S_ + s0 + j0;
  *(uint4*)(dst) = *(const uint4*)&tmp[0];
  *(uint4*)(dst + 8) = *(const uint4*)&tmp[8];
}

// ---------------------------------------------------------------------------
// LayerNorm pair, bf16 in: rows 0..8191 stream0, 8192..16383 stream1
// ---------------------------------------------------------------------------
__global__ __launch_bounds__(256) void ln16_kernel(
    const unsigned short* __restrict__ X0, const unsigned short* __restrict__ X1,
    unsigned short* __restrict__ Yb0, unsigned short* __restrict__ Yb1,
    float* __restrict__ Yf0, float* __restrict__ Yf1,
    const float* __restrict__ gb0, const float* __restrict__ gb1)
{
  int row = blockIdx.x, tid = threadIdx.x;
  int strm = row >> 13, r = row & 8191;
  const unsigned short* X = strm ? X1 : X0;
  unsigned short* Yb = strm ? Yb1 : Yb0;
  float* Yf = strm ? Yf1 : Yf0;
  const float* gb = strm ? gb1 : gb0;       // gamma at [0,512), beta at [512,1024)

  ushort2 xv = *(const ushort2*)(X + (size_t)r * D_ + 2 * tid);
  float v0 = bf2f(xv.x), v1 = bf2f(xv.y);
  float s = v0 + v1, q = v0 * v0 + v1 * v1;
  #pragma unroll
  for (int msk = 1; msk < 64; msk <<= 1) {
    s += __shfl_xor(s, msk);
    q += __shfl_xor(q, msk);
  }
  __shared__ float ss[4], qs[4];
  int wid = tid >> 6;
  if ((tid & 63) == 0) { ss[wid] = s; qs[wid] = q; }
  __syncthreads();
  s = ss[0] + ss[1] + ss[2] + ss[3];
  q = qs[0] + qs[1] + qs[2] + qs[3];
  float mean = s * (1.0f / D_);
  float var  = q * (1.0f / D_) - mean * mean;
  float inv  = rsqrtf(var + 1e-5f);
  float2 gg = *(const float2*)(gb + 2 * tid);
  float2 bb = *(const float2*)(gb + 512 + 2 * tid);
  float o0 = (v0 - mean) * inv * gg.x + bb.x;
  float o1 = (v1 - mean) * inv * gg.y + bb.y;
  if (Yb) {
    unsigned short u[2] = {f2bf(o0), f2bf(o1)};
    *(unsigned int*)(Yb + (size_t)r * D_ + 2 * tid) = *(const unsigned int*)u;
  }
  if (Yf) {
    float2 o; o.x = o0; o.y = o1;
    *(float2*)(Yf + (size_t)r * D_ + 2 * tid) = o;
  }
}

// ---------------------------------------------------------------------------
// MFMA dual-stream cross-blended flash attention v4.
// 256 threads = 4 waves; Q-tile 64 (wave w owns q-rows q0+16w..+15); grid 1024
// blocks (16 qb x 64 bh) -> 3 blocks/CU (LDS 41 KB), no grid cap at 2/CU.
// K-tiles of 64 staged via global_load_lds (wave w stages buffer w), XOR-chunk
// swizzle. QK computed transposed (A=K, B=Q -> C[key][q]); P round-trips
// through a SINGLE per-wave Pl buffer with two-pass PV (img: ii,id; dpt:
// di,dd) - same-wave DS ordering makes the overwrite safe. Plain exp2
// (logits tiny) == exact softmax. Blend 0.5/0.5 at end.
// XCD swizzle: 16 q-blocks of one (b,h) share an XCD for K/V L2 reuse.
// ---------------------------------------------------------------------------
__global__ __launch_bounds__(256, 4) void attn_kernel(
    const unsigned short* __restrict__ Qi, const unsigned short* __restrict__ Ki, int ldi,
    const unsigned short* __restrict__ Vti,
    const unsigned short* __restrict__ Qd, const unsigned short* __restrict__ Kd, int ldd,
    const unsigned short* __restrict__ Vtd,
    unsigned short* __restrict__ oi, unsigned short* __restrict__ od)
{
  __shared__ __align__(16) unsigned short Kls[2][64 * 64];   // [stream][key][dim] swizzled
  __shared__ __align__(16) unsigned short Vls[2][64 * 64];   // [stream][dim][key] swizzled
  __shared__ __align__(16) unsigned short Pl[4][16 * 72];    // [wave][q][key] single stream

  int tid = threadIdx.x;
  // XCD swizzle: id%8 = XCD-affine; bh = (id&7)|((id>>7)<<3), qb = (id>>3)&15
  int id = blockIdx.y * 16 + blockIdx.x;     // 0..1023
  int bh = (id & 7) | ((id >> 7) << 3);
  int qb = (id >> 3) & 15;
  int b = bh >> 3, h = bh & 7;
  int q0 = qb * 64;

  int lane = tid & 63, w = tid >> 6;         // w = 0..3
  int ml = lane & 15, g = lane >> 4;
  int mx = ml & 7;                           // XOR swizzle term for frag reads

  // Q fragments (B-operand): lane holds Q[q0+w*16+ml][dims g*8(+32)]
  short8 qf[2][2];                           // [stream][k-half]
  {
    size_t tok = (size_t)(q0 + w * 16 + ml) * B_ + b;
    const unsigned short* qa_i = Qi + tok * ldi + h * HD_ + g * 8;
    const unsigned short* qa_d = Qd + tok * ldd + h * HD_ + g * 8;
    qf[0][0] = *(const short8*)(qa_i);  qf[0][1] = *(const short8*)(qa_i + 32);
    qf[1][0] = *(const short8*)(qa_d);  qf[1][1] = *(const short8*)(qa_d + 32);
  }

  // staging: wave w stages buffer w (K img, K dpt, V img, V dpt; 8 KB each)
  int srow = lane >> 3;                      // 0..7
  int chg = (lane & 7) ^ srow;               // XOR-swizzled global chunk
  const unsigned short* gbase; size_t s1, s2; unsigned short* lbase;
  if (w == 0)      { gbase = Ki  + ((size_t)srow * B_ + b) * ldi + h * HD_ + chg * 8; s1 = (size_t)B_ * ldi; s2 = s1; lbase = &Kls[0][0]; }
  else if (w == 1) { gbase = Kd  + ((size_t)srow * B_ + b) * ldd + h * HD_ + chg * 8; s1 = (size_t)B_ * ldd; s2 = s1; lbase = &Kls[1][0]; }
  else if (w == 2) { gbase = Vti + (size_t)bh * HD_ * S_ + (size_t)srow * S_ + chg * 8; s1 = S_; s2 = 1; lbase = &Vls[0][0]; }
  else             { gbase = Vtd + (size_t)bh * HD_ * S_ + (size_t)srow * S_ + chg * 8; s1 = S_; s2 = 1; lbase = &Vls[1][0]; }

  f32x4 acc4[4][4];                          // [combo: ii,di,id,dd][hd-tile]
  #pragma unroll
  for (int cb = 0; cb < 4; cb++)
    #pragma unroll
    for (int n = 0; n < 4; n++) acc4[cb][n] = (f32x4){0.f, 0.f, 0.f, 0.f};
  float lI = 0.f, lD = 0.f;
  const float SC = 0.18033688011112042f;     // 0.125 * log2(e)

  for (int kt = 0; kt < S_ / 64; kt++) {
    int k0 = kt * 64;
    __syncthreads();                         // prior tile's reads complete
    {
      const unsigned short* gp = gbase + (size_t)k0 * s2;
      #pragma unroll
      for (int rr = 0; rr < 8; rr++)
        gl_lds16(gp + (size_t)rr * 8 * s1, lbase + rr * 512);
    }
    __syncthreads();                         // staged tile visible

    // two passes: st=0 img (combos ii,id), st=1 dpt (combos di,dd)
    #pragma unroll
    for (int st = 0; st < 2; st++) {
      float* ls = st ? &lD : &lI;
      const unsigned short* Kt = &Kls[st][0];
      // K^T Q -> C[key][q=ml]; exp2; stash P[q][key] in per-wave Pl
      #pragma unroll
      for (int n = 0; n < 4; n++) {
        int rbase = (n * 16 + ml) * 64;
        short8 kf0 = *(const short8*)&Kt[rbase + ((g ^ mx) * 8)];
        short8 kf1 = *(const short8*)&Kt[rbase + (((g + 4) ^ mx) * 8)];
        f32x4 a = (f32x4){0.f, 0.f, 0.f, 0.f};
        a = __builtin_amdgcn_mfma_f32_16x16x32_bf16(kf0, qf[st][0], a, 0, 0, 0);
        a = __builtin_amdgcn_mfma_f32_16x16x32_bf16(kf1, qf[st][1], a, 0, 0, 0);
        float p0 = __builtin_amdgcn_exp2f(a[0] * SC);
        float p1 = __builtin_amdgcn_exp2f(a[1] * SC);
        float p2 = __builtin_amdgcn_exp2f(a[2] * SC);
        float p3 = __builtin_amdgcn_exp2f(a[3] * SC);
        *ls += (p0 + p1) + (p2 + p3);
        uint2 pk; pk.x = pack_bf2(p0, p1); pk.y = pack_bf2(p2, p3);
        *(uint2*)&Pl[w][ml * 72 + n * 16 + g * 4] = pk;
      }
      // PV: this stream's P against BOTH V streams
      #pragma unroll
      for (int c = 0; c < 2; c++) {
        short8 p8 = *(const short8*)&Pl[w][ml * 72 + g * 8 + c * 32];
        #pragma unroll
        for (int n = 0; n < 4; n++) {
          int rbase = (n * 16 + ml) * 64;
          int sc = ((g + 4 * c) ^ mx) * 8;
          short8 vI = *(const short8*)&Vls[0][rbase + sc];
          short8 vD = *(const short8*)&Vls[1][rbase + sc];
          if (st == 0) {
            acc4[0][n] = __builtin_amdgcn_mfma_f32_16x16x32_bf16(p8, vI, acc4[0][n], 0, 0, 0);
            acc4[2][n] = __builtin_amdgcn_mfma_f32_16x16x32_bf16(p8, vD, acc4[2][n], 0, 0, 0);
          } else {
            acc4[1][n] = __builtin_amdgcn_mfma_f32_16x16x32_bf16(p8, vI, acc4[1][n], 0, 0, 0);
            acc4[3][n] = __builtin_amdgcn_mfma_f32_16x16x32_bf16(p8, vD, acc4[3][n], 0, 0, 0);
          }
        }
      }
    }
  }

  // denominators: lane (ml,g) holds partial for q=ml; reduce over g
  lI += __shfl_xor(lI, 16);  lI += __shfl_xor(lI, 32);
  lD += __shfl_xor(lD, 16);  lD += __shfl_xor(lD, 32);
  float invI = 1.0f / lI, invD = 1.0f / lD;

  #pragma unroll
  for (int r = 0; r < 4; r++) {
    float iI = __shfl(invI, g * 4 + r, 16);  // denom for q-row g*4+r lives at lane ml=q
    float iD = __shfl(invD, g * 4 + r, 16);
    int qrow = q0 + w * 16 + g * 4 + r;
    size_t ob = ((size_t)qrow * B_ + b) * D_ + h * HD_;
    #pragma unroll
    for (int n = 0; n < 4; n++) {
      oi[ob + n * 16 + ml] = f2bf(0.5f * (acc4[0][n][r] * iI + acc4[1][n][r] * iD));
      od[ob + n * 16 + ml] = f2bf(0.5f * (acc4[3][n][r] * iD + acc4[2][n][r] * iI));
    }
  }
}

// ---------------------------------------------------------------------------
extern "C" void kernel_launch(void* const* d_in, const int* in_sizes, int n_in,
                              void* d_out, int out_size, void* d_ws, size_t ws_size,
                              hipStream_t stream) {
  const float* src  = (const float*)d_in[0];
  const float* srcd = (const float*)d_in[1];
  const float* pos  = (const float*)d_in[2];
  const float* wA_i = (const float*)d_in[3];
  const float* bA_i = (const float*)d_in[4];
  const float* wA_d = (const float*)d_in[5];
  const float* bA_d = (const float*)d_in[6];
  const float* w1_i = (const float*)d_in[7];
  const float* b1_i = (const float*)d_in[8];
  const float* w2_i = (const float*)d_in[9];
  const float* b2_i = (const float*)d_in[10];
  const float* w1_d = (const float*)d_in[11];
  const float* b1_d = (const float*)d_in[12];
  const float* w2_d = (const float*)d_in[13];
  const float* b2_d = (const float*)d_in[14];
  const float* ln_i = (const float*)d_in[15];
  const float* ln_d = (const float*)d_in[16];

  float* out = (float*)d_out;
  unsigned short* u = (unsigned short*)d_ws;
  const size_t T4 = (size_t)M_ * D_;          // 4,194,304
  const size_t WSZ = (size_t)FF_ * D_;        // 1,048,576 (== 4*DD_)

  // ---- workspace layout (units of T4 ushorts = 8.39 MB; total ~113 MB) ----
  unsigned short* src16  = u;                 // [0,1) -> vt_i after QKV
  unsigned short* srcd16 = u + T4;            // [1,2) -> vt_d after QKV
  unsigned short* qkimg  = u + 2 * T4;        // [2,4)  [M,1024]
  unsigned short* vimg   = u + 4 * T4;        // [4,5)  [M,512]
  unsigned short* dptqkv = u + 5 * T4;        // [5,8)  [M,1536]
  unsigned short* w_i16  = u + 8 * T4;        // weights: 6 x 1,048,576
  unsigned short* w_d16  = w_i16 + WSZ;
  unsigned short* w1i16  = w_d16 + WSZ;
  unsigned short* w2i16  = w1i16 + WSZ;
  unsigned short* w1d16  = w2i16 + WSZ;
  unsigned short* w2d16  = w1d16 + WSZ;
  unsigned short* t16_i  = w2d16 + WSZ;       // pre-LN bf16
  unsigned short* t16_d  = t16_i + T4;
  unsigned short* x16_i  = t16_d + T4;        // post-LN1
  unsigned short* x16_d  = x16_i + T4;
  unsigned short* vt_i   = src16;             // reuse after QKV
  unsigned short* vt_d   = srcd16;
  unsigned short* h16_i  = u;                 // [0,4) FFN hidden (post-attn reuse)
  unsigned short* h16_d  = u + 4 * T4;        // [4,8)
  // d_out overlays (consumed before final LN writes)
  unsigned short* qkin16 = (unsigned short*)out;          // bytes [0, 2T4)
  unsigned short* oi16   = (unsigned short*)out;          // bytes [0, 2T4)
  unsigned short* od16   = (unsigned short*)out + T4;     // bytes [2T4, 4T4)

  dim3 blk(256);

  CvtArgs ca;
  ca.win[0] = wA_i; ca.wout[0] = w_i16;
  ca.win[1] = wA_d; ca.wout[1] = w_d16;
  ca.win[2] = w1_i; ca.wout[2] = w1i16;
  ca.win[3] = w2_i; ca.wout[3] = w2i16;
  ca.win[4] = w1_d; ca.wout[4] = w1d16;
  ca.win[5] = w2_d; ca.wout[5] = w2d16;
  ca.src = src; ca.srcd = srcd; ca.pos = pos;
  ca.src16 = src16; ca.srcd16 = srcd16; ca.qkin16 = qkin16;
  cvt_kernel<<<10240, blk, 0, stream>>>(ca);

  qkv_kernel<<<dim3(24, 64), blk, 0, stream>>>(qkin16, src16, srcd16, w_i16, w_d16,
                                               bA_i, bA_d, qkimg, vimg, dptqkv);
  vtrans_kernel<<<dim3(16, 64, 2), blk, 0, stream>>>(vimg, 512, vt_i, dptqkv + 1024, 1536, vt_d);

  attn_kernel<<<dim3(16, 64), blk, 0, stream>>>(
      qkimg, qkimg + 512, 1024, vt_i, dptqkv, dptqkv + 512, 1536, vt_d, oi16, od16);

  // out-proj + residual(src fp32) -> pre-LN bf16
  pgemm_kernel<<<dim3(4, 64, 2), blk, 0, stream>>>(
      oi16, od16, w_i16 + 3 * DD_, w_d16 + 3 * DD_, bA_i + 1536, bA_d + 1536,
      src, srcd, nullptr, nullptr, t16_i, t16_d, 512, 512, 0);
  ln16_kernel<<<2 * M_, blk, 0, stream>>>(t16_i, t16_d, x16_i, x16_d,
                                          nullptr, nullptr, ln_i, ln_d);
  pgemm_kernel<<<dim3(16, 64, 2), blk, 0, stream>>>(
      x16_i, x16_d, w1i16, w1d16, b1_i, b1_d,
      nullptr, nullptr, nullptr, nullptr, h16_i, h16_d, 2048, 512, 1);
  pgemm_kernel<<<dim3(4, 64, 2), blk, 0, stream>>>(
      h16_i, h16_d, w2i16, w2d16, b2_i, b2_d,
      nullptr, nullptr, x16_i, x16_d, t16_i, t16_d, 512, 2048, 0);
  ln16_kernel<<<2 * M_, blk, 0, stream>>>(t16_i, t16_d, nullptr, nullptr,
                                          out, out + T4, ln_i + 2 * D_, ln_d + 2 * D_);
}